// Round 11
// baseline (202.407 us; speedup 1.0000x reference)
//
#include <hip/hip_runtime.h>
#include <math.h>

typedef __attribute__((ext_vector_type(8))) short bf16x8;
typedef __attribute__((ext_vector_type(4))) float f32x4;
typedef __attribute__((ext_vector_type(16))) float f32x16;

__device__ __forceinline__ ushort f2bf(float f) {
  union { float f; unsigned u; } v; v.f = f;
  return (ushort)((v.u + 0x8000u) >> 16);
}

// async global->LDS, 16B per lane. lds base wave-uniform; lane i lands at base + i*16B.
__device__ __forceinline__ void g2l16(const void* g, void* l) {
  __builtin_amdgcn_global_load_lds((const __attribute__((address_space(1))) unsigned*)g,
                                   (__attribute__((address_space(3))) unsigned*)l, 16, 0, 0);
}

// ---------------- merged cast + zero kernel ----------------
// idx [0,1M): x -> xbf.  [1M,2M): weights -> wcat (Wq scaled).  [2M,3M): zero O32.
__global__ __launch_bounds__(256) void cast_all(const float* __restrict__ x,
                                                const float* __restrict__ Wq,
                                                const float* __restrict__ Wk,
                                                const float* __restrict__ Wv,
                                                const float* __restrict__ Wo,
                                                ushort* __restrict__ xbf,
                                                ushort* __restrict__ wcat,
                                                float4* __restrict__ O32) {
  int i = blockIdx.x * 256 + threadIdx.x;
  if (i < 1048576) {
    float4 v = ((const float4*)x)[i];
    ushort4 u; u.x = f2bf(v.x); u.y = f2bf(v.y); u.z = f2bf(v.z); u.w = f2bf(v.w);
    ((ushort4*)xbf)[i] = u;
  } else if (i < 2097152) {
    int j = i - 1048576;
    int sel = j >> 18;
    const float* src = (sel == 0) ? Wq : (sel == 1) ? Wk : (sel == 2) ? Wv : Wo;
    float scale = (sel == 0) ? 0.125f * 1.44269504088896f : 1.0f;  // fold D^-0.5 * log2e
    float4 v = ((const float4*)src)[j & 0x3FFFF];
    ushort4 u;
    u.x = f2bf(v.x * scale); u.y = f2bf(v.y * scale);
    u.z = f2bf(v.z * scale); u.w = f2bf(v.w * scale);
    ((ushort4*)wcat)[j] = u;
  } else {
    O32[i - 2097152] = float4{0.f, 0.f, 0.f, 0.f};
  }
}

// ---------------- QKV GEMM: C = A @ B^T, 128x128, BK=32, dbuf ----------------
// Q/K planes token-major; V blocks write Vt[bh][d][t] via LDS transpose in the epilogue.
__global__ __launch_bounds__(256) void gemm_qkv(const ushort* __restrict__ A,
                                                const ushort* __restrict__ B,
                                                ushort* __restrict__ C3,
                                                ushort* __restrict__ Vt) {
  const int K = 1024;
  __shared__ __align__(16) ushort smem[17408];   // staging 32KB / transpose T[128][136]
  ushort* As = smem;           // [2][128*32]
  ushort* Bs = smem + 8192;    // [2][128*32]
  const int m0 = blockIdx.y * 128, n0 = blockIdx.x * 128;
  const int tid = threadIdx.x, lane = tid & 63, wid = tid >> 6;
  const int quad = lane >> 4, lc = lane & 15;
  const int lrow = lane >> 2, lcol = (lane & 3) * 8;
  const int wm = (wid >> 1) * 64, wn = (wid & 1) * 64;

  f32x4 acc[4][4] = {};

  auto stage = [&](int k0, int nb) {
    const ushort* Ag = A + (size_t)(m0 + wid * 32 + lrow) * K + k0 + lcol;
    g2l16(Ag, &As[nb * 4096 + wid * 1024]);
    g2l16(Ag + (size_t)16 * K, &As[nb * 4096 + wid * 1024 + 512]);
    const ushort* Bg = B + (size_t)(n0 + wid * 32 + lrow) * K + k0 + lcol;
    g2l16(Bg, &Bs[nb * 4096 + wid * 1024]);
    g2l16(Bg + (size_t)16 * K, &Bs[nb * 4096 + wid * 1024 + 512]);
  };

  stage(0, 0);
  for (int k0 = 0; k0 < K; k0 += 32) {
    const int nb = (k0 >> 5) & 1;
    __syncthreads();
    if (k0 + 32 < K) stage(k0 + 32, nb ^ 1);

    bf16x8 af[4], bfr[4];
#pragma unroll
    for (int t = 0; t < 4; t++)
      af[t] = *(const bf16x8*)&As[nb * 4096 + (wm + t * 16 + lc) * 32 + quad * 8];
#pragma unroll
    for (int t = 0; t < 4; t++)
      bfr[t] = *(const bf16x8*)&Bs[nb * 4096 + (wn + t * 16 + lc) * 32 + quad * 8];
#pragma unroll
    for (int mt = 0; mt < 4; mt++)
#pragma unroll
      for (int nt = 0; nt < 4; nt++)
        acc[mt][nt] = __builtin_amdgcn_mfma_f32_16x16x32_bf16(af[mt], bfr[nt], acc[mt][nt], 0, 0, 0);
  }

  const int sel = n0 >> 10;   // 0=Q, 1=K, 2=V (block-uniform)
  if (sel < 2) {
#pragma unroll
    for (int mt = 0; mt < 4; mt++) {
#pragma unroll
      for (int r = 0; r < 4; r++) {
        int row = m0 + wm + mt * 16 + quad * 4 + r;
#pragma unroll
        for (int nt = 0; nt < 4; nt++) {
          int col = n0 + wn + nt * 16 + lc;
          size_t dst = ((size_t)sel << 22) + (size_t)row * 1024 + (col & 1023);
          C3[dst] = f2bf(acc[mt][nt][r]);
        }
      }
    }
  } else {
    // transpose through LDS: T[d_local 128][token_local 128], pitch 136
    __syncthreads();
#pragma unroll
    for (int mt = 0; mt < 4; mt++)
#pragma unroll
      for (int r = 0; r < 4; r++) {
        int tl = wm + mt * 16 + quad * 4 + r;
#pragma unroll
        for (int nt = 0; nt < 4; nt++)
          smem[(wn + nt * 16 + lc) * 136 + tl] = f2bf(acc[mt][nt][r]);
      }
    __syncthreads();
    const int hd0 = n0 - 2048, b = m0 >> 11, t_base = m0 & 2047;
#pragma unroll
    for (int i = 0; i < 8; i++) {
      int idx = i * 256 + tid;
      int dl = idx >> 4, tc = (idx & 15) * 8;
      uint4 v = *(const uint4*)&smem[dl * 136 + tc];
      int hd = hd0 + dl;
      *(uint4*)(Vt + (size_t)(b * 16 + (hd >> 6)) * 131072 +
                (size_t)(hd & 63) * 2048 + t_base + tc) = v;
    }
  }
}

// ---------------- proj GEMM: out[4096][1024] = attn_out @ Wo^T + bo, BK=64 ----------------
__global__ __launch_bounds__(256) void gemm_proj(const ushort* __restrict__ A,
                                                 const ushort* __restrict__ B,
                                                 float* __restrict__ C,
                                                 const float* __restrict__ bias) {
  const int K = 1024;
  __shared__ __align__(16) ushort As[2][2][128 * 32];
  __shared__ __align__(16) ushort Bs[2][2][64 * 32];
  const int m0 = blockIdx.y * 128, n0 = blockIdx.x * 64;
  const int tid = threadIdx.x, lane = tid & 63, wid = tid >> 6;
  const int quad = lane >> 4, lc = lane & 15;
  const int lrow = lane >> 2, lcol = (lane & 3) * 8;
  const int wm = (wid >> 1) * 64, wn = (wid & 1) * 32;

  f32x4 acc[4][2] = {};

  auto stage = [&](int k0, int nb) {
    const ushort* Ag = A + (size_t)(m0 + wid * 32 + lrow) * K + k0 + lcol;
    g2l16(Ag,                       &As[nb][0][wid * 1024]);
    g2l16(Ag + (size_t)16 * K,      &As[nb][0][wid * 1024 + 512]);
    g2l16(Ag + 32,                  &As[nb][1][wid * 1024]);
    g2l16(Ag + (size_t)16 * K + 32, &As[nb][1][wid * 1024 + 512]);
    const ushort* Bg = B + (size_t)(n0 + wid * 16 + lrow) * K + k0 + lcol;
    g2l16(Bg,      &Bs[nb][0][wid * 512]);
    g2l16(Bg + 32, &Bs[nb][1][wid * 512]);
  };

  stage(0, 0);
  for (int k0 = 0; k0 < K; k0 += 64) {
    const int nb = (k0 >> 6) & 1;
    __syncthreads();
    if (k0 + 64 < K) stage(k0 + 64, nb ^ 1);

#pragma unroll
    for (int ks = 0; ks < 2; ks++) {
      bf16x8 af[4], bfr[2];
#pragma unroll
      for (int t = 0; t < 4; t++)
        af[t] = *(const bf16x8*)&As[nb][ks][(wm + t * 16 + lc) * 32 + quad * 8];
#pragma unroll
      for (int t = 0; t < 2; t++)
        bfr[t] = *(const bf16x8*)&Bs[nb][ks][(wn + t * 16 + lc) * 32 + quad * 8];
#pragma unroll
      for (int mt = 0; mt < 4; mt++)
#pragma unroll
        for (int nt = 0; nt < 2; nt++)
          acc[mt][nt] = __builtin_amdgcn_mfma_f32_16x16x32_bf16(af[mt], bfr[nt], acc[mt][nt], 0, 0, 0);
    }
  }

#pragma unroll
  for (int mt = 0; mt < 4; mt++) {
#pragma unroll
    for (int r = 0; r < 4; r++) {
      int row = m0 + wm + mt * 16 + quad * 4 + r;
#pragma unroll
      for (int nt = 0; nt < 2; nt++) {
        int col = n0 + wn + nt * 16 + lc;
        C[(size_t)row * 1024 + col] = acc[mt][nt][r] + bias[col];
      }
    }
  }
}

// ---------------- flash attention: 64 q per wave — amortized tiles ----------------
// r4-r10 invariant: ~51us regardless of staging mechanism -> per-tile overhead
// (2 barriers + 16 stage ops + softmax chain) vs only ~256cy MFMA is the limit.
// Fix: each wave computes TWO 32-q subtiles per K/V tile. kf loaded once per g64
// (K ds_reads halved per compute), vb loaded once per (half,dg) (V ds_reads halved),
// barriers/stage per tile unchanged -> compute:overhead doubles. Block = 128 q,
// grid (32 bh, 40 f) with r0-proven heavy-first decode. Math per subtile is
// byte-identical to green r5/r10. launch_bounds(128,2): ~190 VGPR, no spill.
__global__ __launch_bounds__(128, 2) void attn_kernel(const ushort* __restrict__ Qb,
                                                      const ushort* __restrict__ Kb,
                                                      const ushort* __restrict__ Vt,
                                                      float* __restrict__ O32,
                                                      float* __restrict__ L32) {
  __shared__ __align__(16) ushort Ks[4096];   // [key 64][d 64] swizzled, 8KB
  __shared__ __align__(16) ushort Vs[4096];   // [d 64][t 64]  swizzled, 8KB

  const int bh = blockIdx.x, b = bh >> 4, h = bh & 15;
  // decode f -> (qi in [0,16), ci): heavy q-blocks first (r0-proven)
  const int f = (int)blockIdx.y;
  int qi, ci;
  if (f < 16)      { qi = 12 + (f >> 2); ci = f & 3; }
  else if (f < 28) { int g = f - 16; int q3 = g / 3; qi = 8 + q3; ci = g - 3 * q3; }
  else if (f < 36) { int g = f - 28; qi = 4 + (g >> 1); ci = g & 1; }
  else             { qi = f - 36; ci = 0; }
  const int t0 = ci * 8;
  const int t1 = min(t0 + 8, 2 * qi + 2);

  const int tid = threadIdx.x, lane = tid & 63, wid = tid >> 6;   // wid 0/1
  const int hi = lane >> 5, ln = lane & 31;
  const int qbw = qi * 128 + wid * 64;        // wave's 64-q base

  const size_t kbase = (size_t)(b * 2048) * 1024 + h * 64;
  const size_t vbase = (size_t)bh * 131072;

  // Q B-fragments: 2 subtiles x 4 d-chunks (slot (hi,j) supplies d = dc*16 + 8*hi + j)
  bf16x8 qf[2][4];
#pragma unroll
  for (int qs = 0; qs < 2; qs++) {
    const ushort* Qp = Qb + kbase + (size_t)(qbw + qs * 32 + ln) * 1024 + hi * 8;
#pragma unroll
    for (int dc = 0; dc < 4; dc++)
      qf[qs][dc] = *(const bf16x8*)(Qp + dc * 16);
  }

  f32x16 o_acc[2][2] = {};                    // [qs][dg]
  float l_own[2] = {0.f, 0.f};

  // staging (r5-proven): wave0 -> K tile, wave1 -> V tile; 8 rows per instr
  // (krow = lane>>3), 8-elem group kcol, source group pre-XOR'd by row&7.
  const int krow = lane >> 3, kcol = lane & 7;
  const int dsw = (kcol ^ krow) << 3;          // swizzled element offset within row

  auto stage = [&](int kb) {
    if (wid == 0) {
      const ushort* gK = Kb + kbase + (size_t)(kb + krow) * 1024 + dsw;
#pragma unroll
      for (int i = 0; i < 8; i++)
        g2l16(gK + (size_t)(i * 8) * 1024, &Ks[i * 512]);
    } else {
      const ushort* gV = Vt + vbase + (size_t)krow * 2048 + kb + dsw;
#pragma unroll
      for (int i = 0; i < 8; i++)
        g2l16(gV + (size_t)(i * 8) * 2048, &Vs[i * 512]);
    }
  };

  const int sx = ln & 7;                       // row&7 for this lane's reads

  for (int kt = t0; kt < t1; kt++) {
    const int kb = kt * 64;
    __syncthreads();                           // previous tile fully read by both waves
    stage(kb);
    __syncthreads();                           // drains each wave's vmcnt, then barrier

#pragma unroll
    for (int g64 = 0; g64 < 2; g64++) {
      if (kb + g64 * 32 > qbw + 63) continue;  // above diagonal for whole wave (uniform)
      const bool skip0 = (kb + g64 * 32 > qbw + 31);  // qs=0 subtile fully masked

      // K fragments once per g64, shared by both q-subtiles
      bf16x8 kf[4];
#pragma unroll
      for (int dc = 0; dc < 4; dc++)
        kf[dc] = *(const bf16x8*)&Ks[(g64 * 32 + ln) * 64 + (((dc * 2 + hi) ^ sx) << 3)];

      unsigned pa[2][2][4];                    // [qs][half][word]
#pragma unroll
      for (int qs = 0; qs < 2; qs++) {
        if (qs == 0 && skip0) continue;
        const int qb2 = qbw + qs * 32;
        f32x16 s;
#pragma unroll
        for (int z = 0; z < 16; z++) s[z] = 0.f;
        __builtin_amdgcn_s_setprio(1);
#pragma unroll
        for (int dc = 0; dc < 4; dc++)
          s = __builtin_amdgcn_mfma_f32_32x32x16_bf16(kf[dc], qf[qs][dc], s, 0, 0, 0);
        __builtin_amdgcn_s_setprio(0);

        // softmax numerator: s[4g+j] = key_local 8g + 4hi + j (within this g64 half)
        unsigned U[8];
        const bool dmask = (kb + g64 * 32 + 31 > qb2);  // wave-uniform diagonal test
        if (dmask) {
          const int c = qb2 + ln - kb - g64 * 32 - hi * 4;   // allowed iff g*8+j <= c
#pragma unroll
          for (int g = 0; g < 4; g++) {
            float e[4];
#pragma unroll
            for (int j = 0; j < 4; j++) {
              float sv = s[g * 4 + j];
              if (g * 8 + j > c) sv = -1e30f;
              e[j] = __builtin_amdgcn_exp2f(sv);
            }
            l_own[qs] += (e[0] + e[1]) + (e[2] + e[3]);
            union { float f; unsigned u; } f0{e[0]}, f1{e[1]}, f2{e[2]}, f3{e[3]};
            U[g * 2]     = __builtin_amdgcn_perm(f1.u + 0x8000u, f0.u + 0x8000u, 0x07060302u);
            U[g * 2 + 1] = __builtin_amdgcn_perm(f3.u + 0x8000u, f2.u + 0x8000u, 0x07060302u);
          }
        } else {
#pragma unroll
          for (int g = 0; g < 4; g++) {
            float e[4];
#pragma unroll
            for (int j = 0; j < 4; j++)
              e[j] = __builtin_amdgcn_exp2f(s[g * 4 + j]);
            l_own[qs] += (e[0] + e[1]) + (e[2] + e[3]);
            union { float f; unsigned u; } f0{e[0]}, f1{e[1]}, f2{e[2]}, f3{e[3]};
            U[g * 2]     = __builtin_amdgcn_perm(f1.u + 0x8000u, f0.u + 0x8000u, 0x07060302u);
            U[g * 2 + 1] = __builtin_amdgcn_perm(f3.u + 0x8000u, f2.u + 0x8000u, 0x07060302u);
          }
        }
#pragma unroll
        for (int half = 0; half < 2; half++)
#pragma unroll
          for (int w = 0; w < 4; w++)
            pa[qs][half][w] = U[half * 4 + w];
      }

      // O += P V: vb loaded once per (half,dg), shared by both q-subtiles
      __builtin_amdgcn_s_setprio(1);
#pragma unroll
      for (int half = 0; half < 2; half++) {
        const int m = g64 * 2 + half;
#pragma unroll
        for (int dg = 0; dg < 2; dg++) {
          const ushort* vrow = &Vs[(dg * 32 + ln) * 64];
          bf16x8 vbf;
          *(unsigned long long*)&vbf =
              *(const unsigned long long*)&vrow[(((2 * m) ^ sx) << 3) + 4 * hi];
          *((unsigned long long*)&vbf + 1) =
              *(const unsigned long long*)&vrow[(((2 * m + 1) ^ sx) << 3) + 4 * hi];
#pragma unroll
          for (int qs = 0; qs < 2; qs++) {
            if (qs == 0 && skip0) continue;
            bf16x8 pfrag;
#pragma unroll
            for (int w = 0; w < 4; w++) ((unsigned*)&pfrag)[w] = pa[qs][half][w];
            o_acc[qs][dg] = __builtin_amdgcn_mfma_f32_32x32x16_bf16(pfrag, vbf, o_acc[qs][dg], 0, 0, 0);
          }
        }
      }
      __builtin_amdgcn_s_setprio(0);
    }
  }

  // epilogue per subtile: l combine + atomic partials (identical to r5/r10 math)
#pragma unroll
  for (int qs = 0; qs < 2; qs++) {
    float lt = l_own[qs] + __shfl_xor(l_own[qs], 32);
    if (hi == 0) atomicAdd(&L32[(size_t)bh * 2048 + qbw + qs * 32 + ln], lt);
#pragma unroll
    for (int r = 0; r < 16; r++) {
      int q = qbw + qs * 32 + (r & 3) + ((r >> 2) << 3) + hi * 4;
      size_t orow = ((size_t)(b * 2048) + q) * 1024 + h * 64 + ln;
      atomicAdd(&O32[orow], o_acc[qs][0][r]);
      atomicAdd(&O32[orow + 32], o_acc[qs][1][r]);
    }
  }
}

// ---------------- normalize: O32/l -> bf16 attn_out ----------------
__global__ __launch_bounds__(256) void normalize_kernel(const float* __restrict__ O32,
                                                        const float* __restrict__ L32,
                                                        ushort* __restrict__ Out) {
  const int row = blockIdx.x;            // 0..4095  (b*2048 + t)
  const int tid = threadIdx.x;
  const int col = tid * 4;
  const int b = row >> 11, t = row & 2047, h = col >> 6;
  const float inv = 1.0f / L32[(size_t)(b * 16 + h) * 2048 + t];
  float4 o = ((const float4*)(O32 + (size_t)row * 1024))[tid];
  ushort4 u;
  u.x = f2bf(o.x * inv); u.y = f2bf(o.y * inv);
  u.z = f2bf(o.z * inv); u.w = f2bf(o.w * inv);
  ((ushort4*)(Out + (size_t)row * 1024))[tid] = u;
}

// ---------------- launcher ----------------
extern "C" void kernel_launch(void* const* d_in, const int* in_sizes, int n_in,
                              void* d_out, int out_size, void* d_ws, size_t ws_size,
                              hipStream_t stream) {
  const float* x  = (const float*)d_in[0];
  const float* Wq = (const float*)d_in[1];
  const float* Wk = (const float*)d_in[2];
  const float* Wv = (const float*)d_in[3];
  const float* Wo = (const float*)d_in[4];
  const float* bo = (const float*)d_in[5];
  float* out = (float*)d_out;

  char* ws = (char*)d_ws;
  ushort* xbf  = (ushort*)(ws);                  //  8 MB: x bf16 (dead after gemm_qkv)
  ushort* wcat = (ushort*)(ws + (8ull  << 20));  //  8 MB: Wcat bf16
  ushort* qkv  = (ushort*)(ws + (16ull << 20));  // 24 MB: Q | K | Vt planes
  ushort* Qp   = qkv;
  ushort* Kp   = qkv + (1ull << 22);
  ushort* Vt   = qkv + (2ull << 22);             // V written directly transposed
  float*  L32  = (float*)ws;                     // 256 KB over dead xbf
  float*  O32  = out;                            // d_out as fp32 accumulator scratch
  ushort* attn_out = Qp;                         // Q plane free after attn

  // cast x+weights, zero O32 (12288 blocks = 3M threads)
  cast_all<<<12288, 256, 0, stream>>>(x, Wq, Wk, Wv, Wo, xbf, wcat, (float4*)O32);

  // QKV = x @ Wcat[0:3072]^T; Q pre-scaled by 0.125*log2e; V transposed in epilogue via LDS
  gemm_qkv<<<dim3(24, 32), 256, 0, stream>>>(xbf, wcat, qkv, Vt);

  hipMemsetAsync(L32, 0, (size_t)32 * 2048 * 4, stream);

  attn_kernel<<<dim3(32, 40), 128, 0, stream>>>(Qp, Kp, Vt, O32, L32);

  normalize_kernel<<<4096, 256, 0, stream>>>(O32, L32, attn_out);

  // out = attn_out @ Wo^T + bo   (overwrites O32 scratch, stream-ordered)
  gemm_proj<<<dim3(16, 32), 256, 0, stream>>>(
      attn_out, wcat + (size_t)3072 * 1024, out, bo);
}

// Round 12
// 196.917 us; speedup vs baseline: 1.0279x; 1.0279x over previous
//
#include <hip/hip_runtime.h>
#include <math.h>

typedef __attribute__((ext_vector_type(8))) short bf16x8;
typedef __attribute__((ext_vector_type(4))) float f32x4;
typedef __attribute__((ext_vector_type(16))) float f32x16;

__device__ __forceinline__ ushort f2bf(float f) {
  union { float f; unsigned u; } v; v.f = f;
  return (ushort)((v.u + 0x8000u) >> 16);
}

// async global->LDS, 16B per lane. lds base wave-uniform; lane i lands at base + i*16B.
__device__ __forceinline__ void g2l16(const void* g, void* l) {
  __builtin_amdgcn_global_load_lds((const __attribute__((address_space(1))) unsigned*)g,
                                   (__attribute__((address_space(3))) unsigned*)l, 16, 0, 0);
}

// ---------------- merged cast + zero kernel ----------------
// idx [0,1M): x -> xbf.  [1M,2M): weights -> wcat (Wq scaled).  [2M,3M): zero O32.
__global__ __launch_bounds__(256) void cast_all(const float* __restrict__ x,
                                                const float* __restrict__ Wq,
                                                const float* __restrict__ Wk,
                                                const float* __restrict__ Wv,
                                                const float* __restrict__ Wo,
                                                ushort* __restrict__ xbf,
                                                ushort* __restrict__ wcat,
                                                float4* __restrict__ O32) {
  int i = blockIdx.x * 256 + threadIdx.x;
  if (i < 1048576) {
    float4 v = ((const float4*)x)[i];
    ushort4 u; u.x = f2bf(v.x); u.y = f2bf(v.y); u.z = f2bf(v.z); u.w = f2bf(v.w);
    ((ushort4*)xbf)[i] = u;
  } else if (i < 2097152) {
    int j = i - 1048576;
    int sel = j >> 18;
    const float* src = (sel == 0) ? Wq : (sel == 1) ? Wk : (sel == 2) ? Wv : Wo;
    float scale = (sel == 0) ? 0.125f * 1.44269504088896f : 1.0f;  // fold D^-0.5 * log2e
    float4 v = ((const float4*)src)[j & 0x3FFFF];
    ushort4 u;
    u.x = f2bf(v.x * scale); u.y = f2bf(v.y * scale);
    u.z = f2bf(v.z * scale); u.w = f2bf(v.w * scale);
    ((ushort4*)wcat)[j] = u;
  } else {
    O32[i - 2097152] = float4{0.f, 0.f, 0.f, 0.f};
  }
}

// ---------------- QKV GEMM: C = A @ B^T, 128x128, BK=32, dbuf ----------------
// Q/K planes token-major; V blocks write Vt[bh][d][t] via LDS transpose in the epilogue.
__global__ __launch_bounds__(256) void gemm_qkv(const ushort* __restrict__ A,
                                                const ushort* __restrict__ B,
                                                ushort* __restrict__ C3,
                                                ushort* __restrict__ Vt) {
  const int K = 1024;
  __shared__ __align__(16) ushort smem[17408];   // staging 32KB / transpose T[128][136]
  ushort* As = smem;           // [2][128*32]
  ushort* Bs = smem + 8192;    // [2][128*32]
  const int m0 = blockIdx.y * 128, n0 = blockIdx.x * 128;
  const int tid = threadIdx.x, lane = tid & 63, wid = tid >> 6;
  const int quad = lane >> 4, lc = lane & 15;
  const int lrow = lane >> 2, lcol = (lane & 3) * 8;
  const int wm = (wid >> 1) * 64, wn = (wid & 1) * 64;

  f32x4 acc[4][4] = {};

  auto stage = [&](int k0, int nb) {
    const ushort* Ag = A + (size_t)(m0 + wid * 32 + lrow) * K + k0 + lcol;
    g2l16(Ag, &As[nb * 4096 + wid * 1024]);
    g2l16(Ag + (size_t)16 * K, &As[nb * 4096 + wid * 1024 + 512]);
    const ushort* Bg = B + (size_t)(n0 + wid * 32 + lrow) * K + k0 + lcol;
    g2l16(Bg, &Bs[nb * 4096 + wid * 1024]);
    g2l16(Bg + (size_t)16 * K, &Bs[nb * 4096 + wid * 1024 + 512]);
  };

  stage(0, 0);
  for (int k0 = 0; k0 < K; k0 += 32) {
    const int nb = (k0 >> 5) & 1;
    __syncthreads();
    if (k0 + 32 < K) stage(k0 + 32, nb ^ 1);

    bf16x8 af[4], bfr[4];
#pragma unroll
    for (int t = 0; t < 4; t++)
      af[t] = *(const bf16x8*)&As[nb * 4096 + (wm + t * 16 + lc) * 32 + quad * 8];
#pragma unroll
    for (int t = 0; t < 4; t++)
      bfr[t] = *(const bf16x8*)&Bs[nb * 4096 + (wn + t * 16 + lc) * 32 + quad * 8];
#pragma unroll
    for (int mt = 0; mt < 4; mt++)
#pragma unroll
      for (int nt = 0; nt < 4; nt++)
        acc[mt][nt] = __builtin_amdgcn_mfma_f32_16x16x32_bf16(af[mt], bfr[nt], acc[mt][nt], 0, 0, 0);
  }

  const int sel = n0 >> 10;   // 0=Q, 1=K, 2=V (block-uniform)
  if (sel < 2) {
#pragma unroll
    for (int mt = 0; mt < 4; mt++) {
#pragma unroll
      for (int r = 0; r < 4; r++) {
        int row = m0 + wm + mt * 16 + quad * 4 + r;
#pragma unroll
        for (int nt = 0; nt < 4; nt++) {
          int col = n0 + wn + nt * 16 + lc;
          size_t dst = ((size_t)sel << 22) + (size_t)row * 1024 + (col & 1023);
          C3[dst] = f2bf(acc[mt][nt][r]);
        }
      }
    }
  } else {
    // transpose through LDS: T[d_local 128][token_local 128], pitch 136
    __syncthreads();
#pragma unroll
    for (int mt = 0; mt < 4; mt++)
#pragma unroll
      for (int r = 0; r < 4; r++) {
        int tl = wm + mt * 16 + quad * 4 + r;
#pragma unroll
        for (int nt = 0; nt < 4; nt++)
          smem[(wn + nt * 16 + lc) * 136 + tl] = f2bf(acc[mt][nt][r]);
      }
    __syncthreads();
    const int hd0 = n0 - 2048, b = m0 >> 11, t_base = m0 & 2047;
#pragma unroll
    for (int i = 0; i < 8; i++) {
      int idx = i * 256 + tid;
      int dl = idx >> 4, tc = (idx & 15) * 8;
      uint4 v = *(const uint4*)&smem[dl * 136 + tc];
      int hd = hd0 + dl;
      *(uint4*)(Vt + (size_t)(b * 16 + (hd >> 6)) * 131072 +
                (size_t)(hd & 63) * 2048 + t_base + tc) = v;
    }
  }
}

// ---------------- proj GEMM: out[4096][1024] = attn_out @ Wo^T + bo, BK=64 ----------------
__global__ __launch_bounds__(256) void gemm_proj(const ushort* __restrict__ A,
                                                 const ushort* __restrict__ B,
                                                 float* __restrict__ C,
                                                 const float* __restrict__ bias) {
  const int K = 1024;
  __shared__ __align__(16) ushort As[2][2][128 * 32];
  __shared__ __align__(16) ushort Bs[2][2][64 * 32];
  const int m0 = blockIdx.y * 128, n0 = blockIdx.x * 64;
  const int tid = threadIdx.x, lane = tid & 63, wid = tid >> 6;
  const int quad = lane >> 4, lc = lane & 15;
  const int lrow = lane >> 2, lcol = (lane & 3) * 8;
  const int wm = (wid >> 1) * 64, wn = (wid & 1) * 32;

  f32x4 acc[4][2] = {};

  auto stage = [&](int k0, int nb) {
    const ushort* Ag = A + (size_t)(m0 + wid * 32 + lrow) * K + k0 + lcol;
    g2l16(Ag,                       &As[nb][0][wid * 1024]);
    g2l16(Ag + (size_t)16 * K,      &As[nb][0][wid * 1024 + 512]);
    g2l16(Ag + 32,                  &As[nb][1][wid * 1024]);
    g2l16(Ag + (size_t)16 * K + 32, &As[nb][1][wid * 1024 + 512]);
    const ushort* Bg = B + (size_t)(n0 + wid * 16 + lrow) * K + k0 + lcol;
    g2l16(Bg,      &Bs[nb][0][wid * 512]);
    g2l16(Bg + 32, &Bs[nb][1][wid * 512]);
  };

  stage(0, 0);
  for (int k0 = 0; k0 < K; k0 += 64) {
    const int nb = (k0 >> 6) & 1;
    __syncthreads();
    if (k0 + 64 < K) stage(k0 + 64, nb ^ 1);

#pragma unroll
    for (int ks = 0; ks < 2; ks++) {
      bf16x8 af[4], bfr[2];
#pragma unroll
      for (int t = 0; t < 4; t++)
        af[t] = *(const bf16x8*)&As[nb][ks][(wm + t * 16 + lc) * 32 + quad * 8];
#pragma unroll
      for (int t = 0; t < 2; t++)
        bfr[t] = *(const bf16x8*)&Bs[nb][ks][(wn + t * 16 + lc) * 32 + quad * 8];
#pragma unroll
      for (int mt = 0; mt < 4; mt++)
#pragma unroll
        for (int nt = 0; nt < 2; nt++)
          acc[mt][nt] = __builtin_amdgcn_mfma_f32_16x16x32_bf16(af[mt], bfr[nt], acc[mt][nt], 0, 0, 0);
    }
  }

#pragma unroll
  for (int mt = 0; mt < 4; mt++) {
#pragma unroll
    for (int r = 0; r < 4; r++) {
      int row = m0 + wm + mt * 16 + quad * 4 + r;
#pragma unroll
      for (int nt = 0; nt < 2; nt++) {
        int col = n0 + wn + nt * 16 + lc;
        C[(size_t)row * 1024 + col] = acc[mt][nt][r] + bias[col];
      }
    }
  }
}

// ---------------- flash attention: 4 waves share one 16KB tile, per-wave math = r10 -------
// r11 lesson: amortize per-tile overhead ACROSS waves, not by serializing into one wave.
// Block = 256 thr (4 waves, 128 q; r0-proven grid (32,40) + heavy-first decode); each
// wave keeps its own 32-q subtile (code path byte-identical to green r10). Staging
// split 4 ways (4 g2l16/wave: waves 0,1 -> K halves, waves 2,3 -> V halves); one
// barrier pair serves 4 waves' compute. LDS 16KB (vs r0's 51KB) -> grid-limited
// 5 blocks/CU = 20 waves/CU. Barriers outside divergence; per-g64 skips inside.
__global__ __launch_bounds__(256, 4) void attn_kernel(const ushort* __restrict__ Qb,
                                                      const ushort* __restrict__ Kb,
                                                      const ushort* __restrict__ Vt,
                                                      float* __restrict__ O32,
                                                      float* __restrict__ L32) {
  __shared__ __align__(16) ushort Ks[4096];   // [key 64][d 64] swizzled, 8KB
  __shared__ __align__(16) ushort Vs[4096];   // [d 64][t 64]  swizzled, 8KB

  const int bh = blockIdx.x, b = bh >> 4, h = bh & 15;
  // decode (qi, ci): low f = heaviest q-blocks first (r0-proven)
  const int f = (int)blockIdx.y;
  int qi, ci;
  if (f < 16)      { qi = 12 + (f >> 2); ci = f & 3; }
  else if (f < 28) { int g = f - 16; int q3 = g / 3; qi = 8 + q3; ci = g - 3 * q3; }
  else if (f < 36) { int g = f - 28; qi = 4 + (g >> 1); ci = g & 1; }
  else             { qi = f - 36; ci = 0; }
  const int t0 = ci * 8;
  const int t1 = min(t0 + 8, 2 * qi + 2);

  const int tid = threadIdx.x, lane = tid & 63, wid = tid >> 6;   // wid 0..3
  const int hi = lane >> 5, ln = lane & 31;
  const int qbw = qi * 128 + wid * 32;
  const int qg = qbw + ln;                    // this lane's q column

  const size_t kbase = (size_t)(b * 2048) * 1024 + h * 64;
  const size_t vbase = (size_t)bh * 131072;

  // Q B-fragments resident: 4 d-chunks of 16 (slot (hi,j) supplies d = dc*16 + 8*hi + j)
  bf16x8 qf[4];
  {
    const ushort* Qp = Qb + kbase + (size_t)qg * 1024 + hi * 8;
#pragma unroll
    for (int dc = 0; dc < 4; dc++)
      qf[dc] = *(const bf16x8*)(Qp + dc * 16);
  }

  f32x16 o_acc[2] = {};
  float l_own = 0.f;

  // staging: 4-way split of the r5/r10 map. Waves 0,1 stage K rows [0,32)/[32,64);
  // waves 2,3 stage V rows likewise. lane covers row half*32 + i*8 + (lane>>3),
  // 8-elem group (lane&7); source group pre-XOR'd by row&7 (LDS dest linear).
  const int krow = lane >> 3, kcol = lane & 7;
  const int dsw = (kcol ^ krow) << 3;          // swizzled element offset within row
  const int shalf = wid & 1;                   // row-half this wave stages

  auto stage = [&](int kb) {
    if (wid < 2) {
      const ushort* gK = Kb + kbase + (size_t)(kb + shalf * 32 + krow) * 1024 + dsw;
#pragma unroll
      for (int i = 0; i < 4; i++)
        g2l16(gK + (size_t)(i * 8) * 1024, &Ks[(shalf * 4 + i) * 512]);
    } else {
      const ushort* gV = Vt + vbase + (size_t)(shalf * 32 + krow) * 2048 + kb + dsw;
#pragma unroll
      for (int i = 0; i < 4; i++)
        g2l16(gV + (size_t)(i * 8) * 2048, &Vs[(shalf * 4 + i) * 512]);
    }
  };

  const int sx = ln & 7;                       // row&7 for this lane's reads

  for (int kt = t0; kt < t1; kt++) {
    const int kb = kt * 64;
    __builtin_amdgcn_s_barrier();              // previous tile fully read by all waves
    stage(kb);
    asm volatile("s_waitcnt vmcnt(0)" ::: "memory");
    __builtin_amdgcn_s_barrier();              // all waves' stages landed

#pragma unroll
    for (int g64 = 0; g64 < 2; g64++) {
      if (kb + g64 * 32 > qbw + 31) continue;  // half fully above diagonal (uniform)
      f32x16 s;
#pragma unroll
      for (int z = 0; z < 16; z++) s[z] = 0.f;
      // S^T(32 keys x 32 q) over d = 64 in 4 chunks of 16
      __builtin_amdgcn_s_setprio(1);
#pragma unroll
      for (int dc = 0; dc < 4; dc++) {
        bf16x8 kf = *(const bf16x8*)&Ks[(g64 * 32 + ln) * 64 + (((dc * 2 + hi) ^ sx) << 3)];
        s = __builtin_amdgcn_mfma_f32_32x32x16_bf16(kf, qf[dc], s, 0, 0, 0);
      }
      __builtin_amdgcn_s_setprio(0);

      // softmax numerator: s[4g+j] = key_local 8g + 4hi + j (within this g64 half)
      unsigned U[8];
      const bool dmask = (kb + g64 * 32 + 31 > qbw);  // wave-uniform diagonal test
      if (dmask) {
        const int c = qg - kb - g64 * 32 - hi * 4;    // allowed iff g*8+j <= c
#pragma unroll
        for (int g = 0; g < 4; g++) {
          float e[4];
#pragma unroll
          for (int j = 0; j < 4; j++) {
            float sv = s[g * 4 + j];
            if (g * 8 + j > c) sv = -1e30f;
            e[j] = __builtin_amdgcn_exp2f(sv);
          }
          l_own += (e[0] + e[1]) + (e[2] + e[3]);
          union { float f; unsigned u; } f0{e[0]}, f1{e[1]}, f2{e[2]}, f3{e[3]};
          U[g * 2]     = __builtin_amdgcn_perm(f1.u + 0x8000u, f0.u + 0x8000u, 0x07060302u);
          U[g * 2 + 1] = __builtin_amdgcn_perm(f3.u + 0x8000u, f2.u + 0x8000u, 0x07060302u);
        }
      } else {
#pragma unroll
        for (int g = 0; g < 4; g++) {
          float e[4];
#pragma unroll
          for (int j = 0; j < 4; j++)
            e[j] = __builtin_amdgcn_exp2f(s[g * 4 + j]);
          l_own += (e[0] + e[1]) + (e[2] + e[3]);
          union { float f; unsigned u; } f0{e[0]}, f1{e[1]}, f2{e[2]}, f3{e[3]};
          U[g * 2]     = __builtin_amdgcn_perm(f1.u + 0x8000u, f0.u + 0x8000u, 0x07060302u);
          U[g * 2 + 1] = __builtin_amdgcn_perm(f3.u + 0x8000u, f2.u + 0x8000u, 0x07060302u);
        }
      }

      // O += P V, fragments m = 2*g64 + half; keymap as r3 (no cross-lane P movement)
      __builtin_amdgcn_s_setprio(1);
#pragma unroll
      for (int half = 0; half < 2; half++) {
        const int m = g64 * 2 + half;
        bf16x8 pfrag;
#pragma unroll
        for (int w = 0; w < 4; w++) ((unsigned*)&pfrag)[w] = U[half * 4 + w];
#pragma unroll
        for (int dg = 0; dg < 2; dg++) {
          const ushort* vrow = &Vs[(dg * 32 + ln) * 64];
          bf16x8 vbf;
          *(unsigned long long*)&vbf =
              *(const unsigned long long*)&vrow[(((2 * m) ^ sx) << 3) + 4 * hi];
          *((unsigned long long*)&vbf + 1) =
              *(const unsigned long long*)&vrow[(((2 * m + 1) ^ sx) << 3) + 4 * hi];
          o_acc[dg] = __builtin_amdgcn_mfma_f32_32x32x16_bf16(pfrag, vbf, o_acc[dg], 0, 0, 0);
        }
      }
      __builtin_amdgcn_s_setprio(0);
    }
  }

  // l: combine hi halves (lane <-> lane^32 hold complementary key sets, same q)
  {
    float lt = l_own + __shfl_xor(l_own, 32);
    if (hi == 0) atomicAdd(&L32[(size_t)bh * 2048 + qg], lt);
  }
  // O partials: lane holds O[q = (r&3)+8*(r>>2)+4hi][dg*32+ln]
#pragma unroll
  for (int r = 0; r < 16; r++) {
    int q = qbw + (r & 3) + ((r >> 2) << 3) + hi * 4;
    size_t orow = ((size_t)(b * 2048) + q) * 1024 + h * 64 + ln;
    atomicAdd(&O32[orow], o_acc[0][r]);
    atomicAdd(&O32[orow + 32], o_acc[1][r]);
  }
}

// ---------------- normalize: O32/l -> bf16 attn_out ----------------
__global__ __launch_bounds__(256) void normalize_kernel(const float* __restrict__ O32,
                                                        const float* __restrict__ L32,
                                                        ushort* __restrict__ Out) {
  const int row = blockIdx.x;            // 0..4095  (b*2048 + t)
  const int tid = threadIdx.x;
  const int col = tid * 4;
  const int b = row >> 11, t = row & 2047, h = col >> 6;
  const float inv = 1.0f / L32[(size_t)(b * 16 + h) * 2048 + t];
  float4 o = ((const float4*)(O32 + (size_t)row * 1024))[tid];
  ushort4 u;
  u.x = f2bf(o.x * inv); u.y = f2bf(o.y * inv);
  u.z = f2bf(o.z * inv); u.w = f2bf(o.w * inv);
  ((ushort4*)(Out + (size_t)row * 1024))[tid] = u;
}

// ---------------- launcher ----------------
extern "C" void kernel_launch(void* const* d_in, const int* in_sizes, int n_in,
                              void* d_out, int out_size, void* d_ws, size_t ws_size,
                              hipStream_t stream) {
  const float* x  = (const float*)d_in[0];
  const float* Wq = (const float*)d_in[1];
  const float* Wk = (const float*)d_in[2];
  const float* Wv = (const float*)d_in[3];
  const float* Wo = (const float*)d_in[4];
  const float* bo = (const float*)d_in[5];
  float* out = (float*)d_out;

  char* ws = (char*)d_ws;
  ushort* xbf  = (ushort*)(ws);                  //  8 MB: x bf16 (dead after gemm_qkv)
  ushort* wcat = (ushort*)(ws + (8ull  << 20));  //  8 MB: Wcat bf16
  ushort* qkv  = (ushort*)(ws + (16ull << 20));  // 24 MB: Q | K | Vt planes
  ushort* Qp   = qkv;
  ushort* Kp   = qkv + (1ull << 22);
  ushort* Vt   = qkv + (2ull << 22);             // V written directly transposed
  float*  L32  = (float*)ws;                     // 256 KB over dead xbf
  float*  O32  = out;                            // d_out as fp32 accumulator scratch
  ushort* attn_out = Qp;                         // Q plane free after attn

  // cast x+weights, zero O32 (12288 blocks = 3M threads)
  cast_all<<<12288, 256, 0, stream>>>(x, Wq, Wk, Wv, Wo, xbf, wcat, (float4*)O32);

  // QKV = x @ Wcat[0:3072]^T; Q pre-scaled by 0.125*log2e; V transposed in epilogue via LDS
  gemm_qkv<<<dim3(24, 32), 256, 0, stream>>>(xbf, wcat, qkv, Vt);

  hipMemsetAsync(L32, 0, (size_t)32 * 2048 * 4, stream);

  attn_kernel<<<dim3(32, 40), 256, 0, stream>>>(Qp, Kp, Vt, O32, L32);

  normalize_kernel<<<4096, 256, 0, stream>>>(O32, L32, attn_out);

  // out = attn_out @ Wo^T + bo   (overwrites O32 scratch, stream-ordered)
  gemm_proj<<<dim3(16, 32), 256, 0, stream>>>(
      attn_out, wcat + (size_t)3072 * 1024, out, bo);
}

// Round 13
// 187.503 us; speedup vs baseline: 1.0795x; 1.0502x over previous
//
#include <hip/hip_runtime.h>
#include <math.h>

typedef __attribute__((ext_vector_type(8))) short bf16x8;
typedef __attribute__((ext_vector_type(4))) float f32x4;
typedef __attribute__((ext_vector_type(16))) float f32x16;

__device__ __forceinline__ ushort f2bf(float f) {
  union { float f; unsigned u; } v; v.f = f;
  return (ushort)((v.u + 0x8000u) >> 16);
}
__device__ __forceinline__ float bf2f(ushort u) {
  union { unsigned u; float f; } v; v.u = (unsigned)u << 16;
  return v.f;
}

// async global->LDS, 16B per lane. lds base wave-uniform; lane i lands at base + i*16B.
__device__ __forceinline__ void g2l16(const void* g, void* l) {
  __builtin_amdgcn_global_load_lds((const __attribute__((address_space(1))) unsigned*)g,
                                   (__attribute__((address_space(3))) unsigned*)l, 16, 0, 0);
}

// ---------------- merged cast kernel ----------------
// idx [0,1M): x -> xbf.  [1M,2M): weights -> wcat (Wq scaled).
// (O32 zeroing removed: slice epilogue uses plain stores, no accumulation target.)
__global__ __launch_bounds__(256) void cast_all(const float* __restrict__ x,
                                                const float* __restrict__ Wq,
                                                const float* __restrict__ Wk,
                                                const float* __restrict__ Wv,
                                                const float* __restrict__ Wo,
                                                ushort* __restrict__ xbf,
                                                ushort* __restrict__ wcat) {
  int i = blockIdx.x * 256 + threadIdx.x;
  if (i < 1048576) {
    float4 v = ((const float4*)x)[i];
    ushort4 u; u.x = f2bf(v.x); u.y = f2bf(v.y); u.z = f2bf(v.z); u.w = f2bf(v.w);
    ((ushort4*)xbf)[i] = u;
  } else {
    int j = i - 1048576;
    int sel = j >> 18;
    const float* src = (sel == 0) ? Wq : (sel == 1) ? Wk : (sel == 2) ? Wv : Wo;
    float scale = (sel == 0) ? 0.125f * 1.44269504088896f : 1.0f;  // fold D^-0.5 * log2e
    float4 v = ((const float4*)src)[j & 0x3FFFF];
    ushort4 u;
    u.x = f2bf(v.x * scale); u.y = f2bf(v.y * scale);
    u.z = f2bf(v.z * scale); u.w = f2bf(v.w * scale);
    ((ushort4*)wcat)[j] = u;
  }
}

// ---------------- QKV GEMM: C = A @ B^T, 128x128, BK=32, dbuf ----------------
// Q/K planes token-major; V blocks write Vt[bh][d][t] via LDS transpose in the epilogue.
__global__ __launch_bounds__(256) void gemm_qkv(const ushort* __restrict__ A,
                                                const ushort* __restrict__ B,
                                                ushort* __restrict__ C3,
                                                ushort* __restrict__ Vt) {
  const int K = 1024;
  __shared__ __align__(16) ushort smem[17408];   // staging 32KB / transpose T[128][136]
  ushort* As = smem;           // [2][128*32]
  ushort* Bs = smem + 8192;    // [2][128*32]
  const int m0 = blockIdx.y * 128, n0 = blockIdx.x * 128;
  const int tid = threadIdx.x, lane = tid & 63, wid = tid >> 6;
  const int quad = lane >> 4, lc = lane & 15;
  const int lrow = lane >> 2, lcol = (lane & 3) * 8;
  const int wm = (wid >> 1) * 64, wn = (wid & 1) * 64;

  f32x4 acc[4][4] = {};

  auto stage = [&](int k0, int nb) {
    const ushort* Ag = A + (size_t)(m0 + wid * 32 + lrow) * K + k0 + lcol;
    g2l16(Ag, &As[nb * 4096 + wid * 1024]);
    g2l16(Ag + (size_t)16 * K, &As[nb * 4096 + wid * 1024 + 512]);
    const ushort* Bg = B + (size_t)(n0 + wid * 32 + lrow) * K + k0 + lcol;
    g2l16(Bg, &Bs[nb * 4096 + wid * 1024]);
    g2l16(Bg + (size_t)16 * K, &Bs[nb * 4096 + wid * 1024 + 512]);
  };

  stage(0, 0);
  for (int k0 = 0; k0 < K; k0 += 32) {
    const int nb = (k0 >> 5) & 1;
    __syncthreads();
    if (k0 + 32 < K) stage(k0 + 32, nb ^ 1);

    bf16x8 af[4], bfr[4];
#pragma unroll
    for (int t = 0; t < 4; t++)
      af[t] = *(const bf16x8*)&As[nb * 4096 + (wm + t * 16 + lc) * 32 + quad * 8];
#pragma unroll
    for (int t = 0; t < 4; t++)
      bfr[t] = *(const bf16x8*)&Bs[nb * 4096 + (wn + t * 16 + lc) * 32 + quad * 8];
#pragma unroll
    for (int mt = 0; mt < 4; mt++)
#pragma unroll
      for (int nt = 0; nt < 4; nt++)
        acc[mt][nt] = __builtin_amdgcn_mfma_f32_16x16x32_bf16(af[mt], bfr[nt], acc[mt][nt], 0, 0, 0);
  }

  const int sel = n0 >> 10;   // 0=Q, 1=K, 2=V (block-uniform)
  if (sel < 2) {
#pragma unroll
    for (int mt = 0; mt < 4; mt++) {
#pragma unroll
      for (int r = 0; r < 4; r++) {
        int row = m0 + wm + mt * 16 + quad * 4 + r;
#pragma unroll
        for (int nt = 0; nt < 4; nt++) {
          int col = n0 + wn + nt * 16 + lc;
          size_t dst = ((size_t)sel << 22) + (size_t)row * 1024 + (col & 1023);
          C3[dst] = f2bf(acc[mt][nt][r]);
        }
      }
    }
  } else {
    // transpose through LDS: T[d_local 128][token_local 128], pitch 136
    __syncthreads();
#pragma unroll
    for (int mt = 0; mt < 4; mt++)
#pragma unroll
      for (int r = 0; r < 4; r++) {
        int tl = wm + mt * 16 + quad * 4 + r;
#pragma unroll
        for (int nt = 0; nt < 4; nt++)
          smem[(wn + nt * 16 + lc) * 136 + tl] = f2bf(acc[mt][nt][r]);
      }
    __syncthreads();
    const int hd0 = n0 - 2048, b = m0 >> 11, t_base = m0 & 2047;
#pragma unroll
    for (int i = 0; i < 8; i++) {
      int idx = i * 256 + tid;
      int dl = idx >> 4, tc = (idx & 15) * 8;
      uint4 v = *(const uint4*)&smem[dl * 136 + tc];
      int hd = hd0 + dl;
      *(uint4*)(Vt + (size_t)(b * 16 + (hd >> 6)) * 131072 +
                (size_t)(hd & 63) * 2048 + t_base + tc) = v;
    }
  }
}

// ---------------- proj GEMM: out[4096][1024] = attn_out @ Wo^T + bo, BK=64 ----------------
__global__ __launch_bounds__(256) void gemm_proj(const ushort* __restrict__ A,
                                                 const ushort* __restrict__ B,
                                                 float* __restrict__ C,
                                                 const float* __restrict__ bias) {
  const int K = 1024;
  __shared__ __align__(16) ushort As[2][2][128 * 32];
  __shared__ __align__(16) ushort Bs[2][2][64 * 32];
  const int m0 = blockIdx.y * 128, n0 = blockIdx.x * 64;
  const int tid = threadIdx.x, lane = tid & 63, wid = tid >> 6;
  const int quad = lane >> 4, lc = lane & 15;
  const int lrow = lane >> 2, lcol = (lane & 3) * 8;
  const int wm = (wid >> 1) * 64, wn = (wid & 1) * 32;

  f32x4 acc[4][2] = {};

  auto stage = [&](int k0, int nb) {
    const ushort* Ag = A + (size_t)(m0 + wid * 32 + lrow) * K + k0 + lcol;
    g2l16(Ag,                       &As[nb][0][wid * 1024]);
    g2l16(Ag + (size_t)16 * K,      &As[nb][0][wid * 1024 + 512]);
    g2l16(Ag + 32,                  &As[nb][1][wid * 1024]);
    g2l16(Ag + (size_t)16 * K + 32, &As[nb][1][wid * 1024 + 512]);
    const ushort* Bg = B + (size_t)(n0 + wid * 16 + lrow) * K + k0 + lcol;
    g2l16(Bg,      &Bs[nb][0][wid * 512]);
    g2l16(Bg + 32, &Bs[nb][1][wid * 512]);
  };

  stage(0, 0);
  for (int k0 = 0; k0 < K; k0 += 64) {
    const int nb = (k0 >> 6) & 1;
    __syncthreads();
    if (k0 + 64 < K) stage(k0 + 64, nb ^ 1);

#pragma unroll
    for (int ks = 0; ks < 2; ks++) {
      bf16x8 af[4], bfr[2];
#pragma unroll
      for (int t = 0; t < 4; t++)
        af[t] = *(const bf16x8*)&As[nb][ks][(wm + t * 16 + lc) * 32 + quad * 8];
#pragma unroll
      for (int t = 0; t < 2; t++)
        bfr[t] = *(const bf16x8*)&Bs[nb][ks][(wn + t * 16 + lc) * 32 + quad * 8];
#pragma unroll
      for (int mt = 0; mt < 4; mt++)
#pragma unroll
        for (int nt = 0; nt < 2; nt++)
          acc[mt][nt] = __builtin_amdgcn_mfma_f32_16x16x32_bf16(af[mt], bfr[nt], acc[mt][nt], 0, 0, 0);
    }
  }

#pragma unroll
  for (int mt = 0; mt < 4; mt++) {
#pragma unroll
    for (int r = 0; r < 4; r++) {
      int row = m0 + wm + mt * 16 + quad * 4 + r;
#pragma unroll
      for (int nt = 0; nt < 2; nt++) {
        int col = n0 + wn + nt * 16 + lc;
        C[(size_t)row * 1024 + col] = acc[mt][nt][r] + bias[col];
      }
    }
  }
}

// ---------------- flash attention: r12-green base, ATOMIC-FREE slice epilogue -------------
// r4-r12 invariant: ~51-62us across 5 schedules; WRITE_SIZE 41.6MB == 10.5M fp32
// atomicAdds == L2-RMW floor (~35-50us at ~128ch x 1op/2cy). Fix: each (qi,ci)
// chunk block PLAIN-STORES its O-partial into a chunk-indexed slice (sole writer
// per slice/row/col -> no RMW, no zeroing). ci=0 -> f32 slice0 (=out); ci=1/2/3 ->
// compact bf16 slices in dead workspace. normalize sums nch(row) slices.
// Grid/decode/staging/compute byte-identical to green r12. L32 atomics kept (163K).
__global__ __launch_bounds__(256, 4) void attn_kernel(const ushort* __restrict__ Qb,
                                                      const ushort* __restrict__ Kb,
                                                      const ushort* __restrict__ Vt,
                                                      float* __restrict__ S0,
                                                      ushort* __restrict__ S1,
                                                      ushort* __restrict__ S2,
                                                      ushort* __restrict__ S3,
                                                      float* __restrict__ L32) {
  __shared__ __align__(16) ushort Ks[4096];   // [key 64][d 64] swizzled, 8KB
  __shared__ __align__(16) ushort Vs[4096];   // [d 64][t 64]  swizzled, 8KB

  const int bh = blockIdx.x, b = bh >> 4, h = bh & 15;
  // decode (qi, ci): low f = heaviest q-blocks first (r0-proven)
  const int f = (int)blockIdx.y;
  int qi, ci;
  if (f < 16)      { qi = 12 + (f >> 2); ci = f & 3; }
  else if (f < 28) { int g = f - 16; int q3 = g / 3; qi = 8 + q3; ci = g - 3 * q3; }
  else if (f < 36) { int g = f - 28; qi = 4 + (g >> 1); ci = g & 1; }
  else             { qi = f - 36; ci = 0; }
  const int t0 = ci * 8;
  const int t1 = min(t0 + 8, 2 * qi + 2);

  const int tid = threadIdx.x, lane = tid & 63, wid = tid >> 6;   // wid 0..3
  const int hi = lane >> 5, ln = lane & 31;
  const int qbw = qi * 128 + wid * 32;
  const int qg = qbw + ln;                    // this lane's q column

  const size_t kbase = (size_t)(b * 2048) * 1024 + h * 64;
  const size_t vbase = (size_t)bh * 131072;

  // Q B-fragments resident: 4 d-chunks of 16 (slot (hi,j) supplies d = dc*16 + 8*hi + j)
  bf16x8 qf[4];
  {
    const ushort* Qp = Qb + kbase + (size_t)qg * 1024 + hi * 8;
#pragma unroll
    for (int dc = 0; dc < 4; dc++)
      qf[dc] = *(const bf16x8*)(Qp + dc * 16);
  }

  f32x16 o_acc[2] = {};
  float l_own = 0.f;

  // staging: 4-way split (waves 0,1 -> K halves; 2,3 -> V halves); source group
  // pre-XOR'd by row&7 (LDS dest linear).
  const int krow = lane >> 3, kcol = lane & 7;
  const int dsw = (kcol ^ krow) << 3;          // swizzled element offset within row
  const int shalf = wid & 1;                   // row-half this wave stages

  auto stage = [&](int kb) {
    if (wid < 2) {
      const ushort* gK = Kb + kbase + (size_t)(kb + shalf * 32 + krow) * 1024 + dsw;
#pragma unroll
      for (int i = 0; i < 4; i++)
        g2l16(gK + (size_t)(i * 8) * 1024, &Ks[(shalf * 4 + i) * 512]);
    } else {
      const ushort* gV = Vt + vbase + (size_t)(shalf * 32 + krow) * 2048 + kb + dsw;
#pragma unroll
      for (int i = 0; i < 4; i++)
        g2l16(gV + (size_t)(i * 8) * 2048, &Vs[(shalf * 4 + i) * 512]);
    }
  };

  const int sx = ln & 7;                       // row&7 for this lane's reads

  for (int kt = t0; kt < t1; kt++) {
    const int kb = kt * 64;
    __builtin_amdgcn_s_barrier();              // previous tile fully read by all waves
    stage(kb);
    asm volatile("s_waitcnt vmcnt(0)" ::: "memory");
    __builtin_amdgcn_s_barrier();              // all waves' stages landed

#pragma unroll
    for (int g64 = 0; g64 < 2; g64++) {
      if (kb + g64 * 32 > qbw + 31) continue;  // half fully above diagonal (uniform)
      f32x16 s;
#pragma unroll
      for (int z = 0; z < 16; z++) s[z] = 0.f;
      // S^T(32 keys x 32 q) over d = 64 in 4 chunks of 16
      __builtin_amdgcn_s_setprio(1);
#pragma unroll
      for (int dc = 0; dc < 4; dc++) {
        bf16x8 kf = *(const bf16x8*)&Ks[(g64 * 32 + ln) * 64 + (((dc * 2 + hi) ^ sx) << 3)];
        s = __builtin_amdgcn_mfma_f32_32x32x16_bf16(kf, qf[dc], s, 0, 0, 0);
      }
      __builtin_amdgcn_s_setprio(0);

      // softmax numerator: s[4g+j] = key_local 8g + 4hi + j (within this g64 half)
      unsigned U[8];
      const bool dmask = (kb + g64 * 32 + 31 > qbw);  // wave-uniform diagonal test
      if (dmask) {
        const int c = qg - kb - g64 * 32 - hi * 4;    // allowed iff g*8+j <= c
#pragma unroll
        for (int g = 0; g < 4; g++) {
          float e[4];
#pragma unroll
          for (int j = 0; j < 4; j++) {
            float sv = s[g * 4 + j];
            if (g * 8 + j > c) sv = -1e30f;
            e[j] = __builtin_amdgcn_exp2f(sv);
          }
          l_own += (e[0] + e[1]) + (e[2] + e[3]);
          union { float f; unsigned u; } f0{e[0]}, f1{e[1]}, f2{e[2]}, f3{e[3]};
          U[g * 2]     = __builtin_amdgcn_perm(f1.u + 0x8000u, f0.u + 0x8000u, 0x07060302u);
          U[g * 2 + 1] = __builtin_amdgcn_perm(f3.u + 0x8000u, f2.u + 0x8000u, 0x07060302u);
        }
      } else {
#pragma unroll
        for (int g = 0; g < 4; g++) {
          float e[4];
#pragma unroll
          for (int j = 0; j < 4; j++)
            e[j] = __builtin_amdgcn_exp2f(s[g * 4 + j]);
          l_own += (e[0] + e[1]) + (e[2] + e[3]);
          union { float f; unsigned u; } f0{e[0]}, f1{e[1]}, f2{e[2]}, f3{e[3]};
          U[g * 2]     = __builtin_amdgcn_perm(f1.u + 0x8000u, f0.u + 0x8000u, 0x07060302u);
          U[g * 2 + 1] = __builtin_amdgcn_perm(f3.u + 0x8000u, f2.u + 0x8000u, 0x07060302u);
        }
      }

      // O += P V, fragments m = 2*g64 + half; keymap as r3 (no cross-lane P movement)
      __builtin_amdgcn_s_setprio(1);
#pragma unroll
      for (int half = 0; half < 2; half++) {
        const int m = g64 * 2 + half;
        bf16x8 pfrag;
#pragma unroll
        for (int w = 0; w < 4; w++) ((unsigned*)&pfrag)[w] = U[half * 4 + w];
#pragma unroll
        for (int dg = 0; dg < 2; dg++) {
          const ushort* vrow = &Vs[(dg * 32 + ln) * 64];
          bf16x8 vbf;
          *(unsigned long long*)&vbf =
              *(const unsigned long long*)&vrow[(((2 * m) ^ sx) << 3) + 4 * hi];
          *((unsigned long long*)&vbf + 1) =
              *(const unsigned long long*)&vrow[(((2 * m + 1) ^ sx) << 3) + 4 * hi];
          o_acc[dg] = __builtin_amdgcn_mfma_f32_32x32x16_bf16(pfrag, vbf, o_acc[dg], 0, 0, 0);
        }
      }
      __builtin_amdgcn_s_setprio(0);
    }
  }

  // l: combine hi halves (lane <-> lane^32 hold complementary key sets, same q)
  {
    float lt = l_own + __shfl_xor(l_own, 32);
    if (hi == 0) atomicAdd(&L32[(size_t)bh * 2048 + qg], lt);
  }
  // O partials: PLAIN stores to this chunk's slice (sole writer; no RMW)
  if (ci == 0) {
#pragma unroll
    for (int r = 0; r < 16; r++) {
      int q = qbw + (r & 3) + ((r >> 2) << 3) + hi * 4;
      size_t orow = ((size_t)(b * 2048) + q) * 1024 + h * 64 + ln;
      S0[orow] = o_acc[0][r];
      S0[orow + 32] = o_acc[1][r];
    }
  } else {
    ushort* Sp = (ci == 1) ? S1 : (ci == 2) ? S2 : S3;
    const int roff = (ci == 1) ? 512 : (ci == 2) ? 1024 : 1536;
    const int rcnt = 2048 - roff;              // rows per batch in this slice
#pragma unroll
    for (int r = 0; r < 16; r++) {
      int q = qbw + (r & 3) + ((r >> 2) << 3) + hi * 4;
      size_t srow = ((size_t)(b * rcnt) + (q - roff)) * 1024 + h * 64 + ln;
      Sp[srow] = f2bf(o_acc[0][r]);
      Sp[srow + 32] = f2bf(o_acc[1][r]);
    }
  }
}

// ---------------- normalize: sum slices, /l -> bf16 attn_out ----------------
__global__ __launch_bounds__(256) void normalize_kernel(const float* __restrict__ S0,
                                                        const ushort* __restrict__ S1,
                                                        const ushort* __restrict__ S2,
                                                        const ushort* __restrict__ S3,
                                                        const float* __restrict__ L32,
                                                        ushort* __restrict__ Out) {
  const int row = blockIdx.x;            // 0..4095  (b*2048 + t)
  const int tid = threadIdx.x;
  const int col = tid * 4;
  const int b = row >> 11, t = row & 2047, h = col >> 6;
  const int qi = t >> 7;
  const int nch = (2 * qi + 9) >> 3;     // chunks this row received (1..4)
  float4 o = ((const float4*)(S0 + (size_t)row * 1024))[tid];
  if (nch > 1) {
    ushort4 p = ((const ushort4*)(S1 + ((size_t)(b * 1536) + t - 512) * 1024))[tid];
    o.x += bf2f(p.x); o.y += bf2f(p.y); o.z += bf2f(p.z); o.w += bf2f(p.w);
  }
  if (nch > 2) {
    ushort4 p = ((const ushort4*)(S2 + ((size_t)(b * 1024) + t - 1024) * 1024))[tid];
    o.x += bf2f(p.x); o.y += bf2f(p.y); o.z += bf2f(p.z); o.w += bf2f(p.w);
  }
  if (nch > 3) {
    ushort4 p = ((const ushort4*)(S3 + ((size_t)(b * 512) + t - 1536) * 1024))[tid];
    o.x += bf2f(p.x); o.y += bf2f(p.y); o.z += bf2f(p.z); o.w += bf2f(p.w);
  }
  const float inv = 1.0f / L32[(size_t)(b * 16 + h) * 2048 + t];
  ushort4 u;
  u.x = f2bf(o.x * inv); u.y = f2bf(o.y * inv);
  u.z = f2bf(o.z * inv); u.w = f2bf(o.w * inv);
  ((ushort4*)(Out + (size_t)row * 1024))[tid] = u;
}

// ---------------- launcher ----------------
extern "C" void kernel_launch(void* const* d_in, const int* in_sizes, int n_in,
                              void* d_out, int out_size, void* d_ws, size_t ws_size,
                              hipStream_t stream) {
  const float* x  = (const float*)d_in[0];
  const float* Wq = (const float*)d_in[1];
  const float* Wk = (const float*)d_in[2];
  const float* Wv = (const float*)d_in[3];
  const float* Wo = (const float*)d_in[4];
  const float* bo = (const float*)d_in[5];
  float* out = (float*)d_out;

  char* ws = (char*)d_ws;
  ushort* xbf  = (ushort*)(ws);                  //  8 MB: x bf16 (dead after gemm_qkv)
  ushort* wcat = (ushort*)(ws + (8ull  << 20));  //  8 MB: Wcat bf16 (rows<3072 dead after qkv)
  ushort* qkv  = (ushort*)(ws + (16ull << 20));  // 24 MB: Q | K | Vt planes
  ushort* Qp   = qkv;
  ushort* Kp   = qkv + (1ull << 22);
  ushort* Vt   = qkv + (2ull << 22);             // V written directly transposed
  // partial slices in dead space [ws, ws+14MB): xbf + dead QKV-weight rows of wcat
  ushort* S1   = (ushort*)(ws);                  // 6 MB: rows q>=512  (bf16)
  ushort* S2   = (ushort*)(ws + (6ull  << 20));  // 4 MB: rows q>=1024 (bf16)
  ushort* S3   = (ushort*)(ws + (10ull << 20));  // 2 MB: rows q>=1536 (bf16)
  float*  L32  = (float*)(ws + (12ull << 20));   // 256 KB (dead wcat rows)
  float*  S0   = out;                            // d_out as f32 slice-0 scratch
  ushort* attn_out = Qp;                         // Q plane free after attn

  // cast x+weights (8192 blocks = 2M threads; O32 zeroing no longer needed)
  cast_all<<<8192, 256, 0, stream>>>(x, Wq, Wk, Wv, Wo, xbf, wcat);

  // QKV = x @ Wcat[0:3072]^T; Q pre-scaled by 0.125*log2e; V transposed in epilogue via LDS
  gemm_qkv<<<dim3(24, 32), 256, 0, stream>>>(xbf, wcat, qkv, Vt);

  hipMemsetAsync(L32, 0, (size_t)32 * 2048 * 4, stream);

  attn_kernel<<<dim3(32, 40), 256, 0, stream>>>(Qp, Kp, Vt, S0, S1, S2, S3, L32);

  normalize_kernel<<<4096, 256, 0, stream>>>(S0, S1, S2, S3, L32, attn_out);

  // out = attn_out @ Wo^T + bo   (overwrites S0 scratch, stream-ordered)
  gemm_proj<<<dim3(16, 32), 256, 0, stream>>>(
      attn_out, wcat + (size_t)3072 * 1024, out, bo);
}

// Round 14
// 184.446 us; speedup vs baseline: 1.0974x; 1.0166x over previous
//
#include <hip/hip_runtime.h>
#include <math.h>

typedef __attribute__((ext_vector_type(8))) short bf16x8;
typedef __attribute__((ext_vector_type(4))) float f32x4;
typedef __attribute__((ext_vector_type(16))) float f32x16;

__device__ __forceinline__ ushort f2bf(float f) {
  union { float f; unsigned u; } v; v.f = f;
  return (ushort)((v.u + 0x8000u) >> 16);
}
__device__ __forceinline__ float bf2f(ushort u) {
  union { unsigned u; float f; } v; v.u = (unsigned)u << 16;
  return v.f;
}

// async global->LDS, 16B per lane. lds base wave-uniform; lane i lands at base + i*16B.
__device__ __forceinline__ void g2l16(const void* g, void* l) {
  __builtin_amdgcn_global_load_lds((const __attribute__((address_space(1))) unsigned*)g,
                                   (__attribute__((address_space(3))) unsigned*)l, 16, 0, 0);
}

// ---------------- merged cast kernel ----------------
// idx [0,1M): x -> xbf.  [1M,2M): weights -> wcat (Wq scaled).
__global__ __launch_bounds__(256) void cast_all(const float* __restrict__ x,
                                                const float* __restrict__ Wq,
                                                const float* __restrict__ Wk,
                                                const float* __restrict__ Wv,
                                                const float* __restrict__ Wo,
                                                ushort* __restrict__ xbf,
                                                ushort* __restrict__ wcat) {
  int i = blockIdx.x * 256 + threadIdx.x;
  if (i < 1048576) {
    float4 v = ((const float4*)x)[i];
    ushort4 u; u.x = f2bf(v.x); u.y = f2bf(v.y); u.z = f2bf(v.z); u.w = f2bf(v.w);
    ((ushort4*)xbf)[i] = u;
  } else {
    int j = i - 1048576;
    int sel = j >> 18;
    const float* src = (sel == 0) ? Wq : (sel == 1) ? Wk : (sel == 2) ? Wv : Wo;
    float scale = (sel == 0) ? 0.125f * 1.44269504088896f : 1.0f;  // fold D^-0.5 * log2e
    float4 v = ((const float4*)src)[j & 0x3FFFF];
    ushort4 u;
    u.x = f2bf(v.x * scale); u.y = f2bf(v.y * scale);
    u.z = f2bf(v.z * scale); u.w = f2bf(v.w * scale);
    ((ushort4*)wcat)[j] = u;
  }
}

// ---------------- QKV GEMM: C = A @ B^T, 128x128, BK=32, dbuf ----------------
// Q/K planes token-major; V blocks write Vt[bh][d][t] via LDS transpose in the epilogue.
__global__ __launch_bounds__(256) void gemm_qkv(const ushort* __restrict__ A,
                                                const ushort* __restrict__ B,
                                                ushort* __restrict__ C3,
                                                ushort* __restrict__ Vt) {
  const int K = 1024;
  __shared__ __align__(16) ushort smem[17408];   // staging 32KB / transpose T[128][136]
  ushort* As = smem;           // [2][128*32]
  ushort* Bs = smem + 8192;    // [2][128*32]
  const int m0 = blockIdx.y * 128, n0 = blockIdx.x * 128;
  const int tid = threadIdx.x, lane = tid & 63, wid = tid >> 6;
  const int quad = lane >> 4, lc = lane & 15;
  const int lrow = lane >> 2, lcol = (lane & 3) * 8;
  const int wm = (wid >> 1) * 64, wn = (wid & 1) * 64;

  f32x4 acc[4][4] = {};

  auto stage = [&](int k0, int nb) {
    const ushort* Ag = A + (size_t)(m0 + wid * 32 + lrow) * K + k0 + lcol;
    g2l16(Ag, &As[nb * 4096 + wid * 1024]);
    g2l16(Ag + (size_t)16 * K, &As[nb * 4096 + wid * 1024 + 512]);
    const ushort* Bg = B + (size_t)(n0 + wid * 32 + lrow) * K + k0 + lcol;
    g2l16(Bg, &Bs[nb * 4096 + wid * 1024]);
    g2l16(Bg + (size_t)16 * K, &Bs[nb * 4096 + wid * 1024 + 512]);
  };

  stage(0, 0);
  for (int k0 = 0; k0 < K; k0 += 32) {
    const int nb = (k0 >> 5) & 1;
    __syncthreads();
    if (k0 + 32 < K) stage(k0 + 32, nb ^ 1);

    bf16x8 af[4], bfr[4];
#pragma unroll
    for (int t = 0; t < 4; t++)
      af[t] = *(const bf16x8*)&As[nb * 4096 + (wm + t * 16 + lc) * 32 + quad * 8];
#pragma unroll
    for (int t = 0; t < 4; t++)
      bfr[t] = *(const bf16x8*)&Bs[nb * 4096 + (wn + t * 16 + lc) * 32 + quad * 8];
#pragma unroll
    for (int mt = 0; mt < 4; mt++)
#pragma unroll
      for (int nt = 0; nt < 4; nt++)
        acc[mt][nt] = __builtin_amdgcn_mfma_f32_16x16x32_bf16(af[mt], bfr[nt], acc[mt][nt], 0, 0, 0);
  }

  const int sel = n0 >> 10;   // 0=Q, 1=K, 2=V (block-uniform)
  if (sel < 2) {
#pragma unroll
    for (int mt = 0; mt < 4; mt++) {
#pragma unroll
      for (int r = 0; r < 4; r++) {
        int row = m0 + wm + mt * 16 + quad * 4 + r;
#pragma unroll
        for (int nt = 0; nt < 4; nt++) {
          int col = n0 + wn + nt * 16 + lc;
          size_t dst = ((size_t)sel << 22) + (size_t)row * 1024 + (col & 1023);
          C3[dst] = f2bf(acc[mt][nt][r]);
        }
      }
    }
  } else {
    // transpose through LDS: T[d_local 128][token_local 128], pitch 136
    __syncthreads();
#pragma unroll
    for (int mt = 0; mt < 4; mt++)
#pragma unroll
      for (int r = 0; r < 4; r++) {
        int tl = wm + mt * 16 + quad * 4 + r;
#pragma unroll
        for (int nt = 0; nt < 4; nt++)
          smem[(wn + nt * 16 + lc) * 136 + tl] = f2bf(acc[mt][nt][r]);
      }
    __syncthreads();
    const int hd0 = n0 - 2048, b = m0 >> 11, t_base = m0 & 2047;
#pragma unroll
    for (int i = 0; i < 8; i++) {
      int idx = i * 256 + tid;
      int dl = idx >> 4, tc = (idx & 15) * 8;
      uint4 v = *(const uint4*)&smem[dl * 136 + tc];
      int hd = hd0 + dl;
      *(uint4*)(Vt + (size_t)(b * 16 + (hd >> 6)) * 131072 +
                (size_t)(hd & 63) * 2048 + t_base + tc) = v;
    }
  }
}

// ---------------- proj GEMM: out[4096][1024] = attn_out @ Wo^T + bo, BK=64 ----------------
__global__ __launch_bounds__(256) void gemm_proj(const ushort* __restrict__ A,
                                                 const ushort* __restrict__ B,
                                                 float* __restrict__ C,
                                                 const float* __restrict__ bias) {
  const int K = 1024;
  __shared__ __align__(16) ushort As[2][2][128 * 32];
  __shared__ __align__(16) ushort Bs[2][2][64 * 32];
  const int m0 = blockIdx.y * 128, n0 = blockIdx.x * 64;
  const int tid = threadIdx.x, lane = tid & 63, wid = tid >> 6;
  const int quad = lane >> 4, lc = lane & 15;
  const int lrow = lane >> 2, lcol = (lane & 3) * 8;
  const int wm = (wid >> 1) * 64, wn = (wid & 1) * 32;

  f32x4 acc[4][2] = {};

  auto stage = [&](int k0, int nb) {
    const ushort* Ag = A + (size_t)(m0 + wid * 32 + lrow) * K + k0 + lcol;
    g2l16(Ag,                       &As[nb][0][wid * 1024]);
    g2l16(Ag + (size_t)16 * K,      &As[nb][0][wid * 1024 + 512]);
    g2l16(Ag + 32,                  &As[nb][1][wid * 1024]);
    g2l16(Ag + (size_t)16 * K + 32, &As[nb][1][wid * 1024 + 512]);
    const ushort* Bg = B + (size_t)(n0 + wid * 16 + lrow) * K + k0 + lcol;
    g2l16(Bg,      &Bs[nb][0][wid * 512]);
    g2l16(Bg + 32, &Bs[nb][1][wid * 512]);
  };

  stage(0, 0);
  for (int k0 = 0; k0 < K; k0 += 64) {
    const int nb = (k0 >> 6) & 1;
    __syncthreads();
    if (k0 + 64 < K) stage(k0 + 64, nb ^ 1);

#pragma unroll
    for (int ks = 0; ks < 2; ks++) {
      bf16x8 af[4], bfr[2];
#pragma unroll
      for (int t = 0; t < 4; t++)
        af[t] = *(const bf16x8*)&As[nb][ks][(wm + t * 16 + lc) * 32 + quad * 8];
#pragma unroll
      for (int t = 0; t < 2; t++)
        bfr[t] = *(const bf16x8*)&Bs[nb][ks][(wn + t * 16 + lc) * 32 + quad * 8];
#pragma unroll
      for (int mt = 0; mt < 4; mt++)
#pragma unroll
        for (int nt = 0; nt < 2; nt++)
          acc[mt][nt] = __builtin_amdgcn_mfma_f32_16x16x32_bf16(af[mt], bfr[nt], acc[mt][nt], 0, 0, 0);
    }
  }

#pragma unroll
  for (int mt = 0; mt < 4; mt++) {
#pragma unroll
    for (int r = 0; r < 4; r++) {
      int row = m0 + wm + mt * 16 + quad * 4 + r;
#pragma unroll
      for (int nt = 0; nt < 2; nt++) {
        int col = n0 + wn + nt * 16 + lc;
        C[(size_t)row * 1024 + col] = acc[mt][nt][r] + bias[col];
      }
    }
  }
}

// ---------------- flash attention: r13 base + double-buffered staging ----------------
// r13 (green, slices) was single-buffered: per tile stage -> vmcnt(0) (~600cy L2
// latency, zero overlap) -> barrier -> compute, two barriers/tile. This round's single
// change: 2-buffer dbuf (r0-r3-proven pattern): loop head __syncthreads() drains the
// prefetch issued LAST iteration (compiler emits vmcnt(0) before s_barrier), then
// prefetch tile kt+1 into buf nb^1 while computing tile kt from buf nb. One barrier
// per tile; the L2 latency hides under compute. Everything else byte-identical to r13.
__global__ __launch_bounds__(256, 4) void attn_kernel(const ushort* __restrict__ Qb,
                                                      const ushort* __restrict__ Kb,
                                                      const ushort* __restrict__ Vt,
                                                      float* __restrict__ S0,
                                                      ushort* __restrict__ S1,
                                                      ushort* __restrict__ S2,
                                                      ushort* __restrict__ S3,
                                                      float* __restrict__ L32) {
  __shared__ __align__(16) ushort Ks[2][4096];   // [buf][key 64][d 64] swizzled, 16KB
  __shared__ __align__(16) ushort Vs[2][4096];   // [buf][d 64][t 64]  swizzled, 16KB

  const int bh = blockIdx.x, b = bh >> 4, h = bh & 15;
  // decode (qi, ci): low f = heaviest q-blocks first (r0-proven)
  const int f = (int)blockIdx.y;
  int qi, ci;
  if (f < 16)      { qi = 12 + (f >> 2); ci = f & 3; }
  else if (f < 28) { int g = f - 16; int q3 = g / 3; qi = 8 + q3; ci = g - 3 * q3; }
  else if (f < 36) { int g = f - 28; qi = 4 + (g >> 1); ci = g & 1; }
  else             { qi = f - 36; ci = 0; }
  const int t0 = ci * 8;
  const int t1 = min(t0 + 8, 2 * qi + 2);

  const int tid = threadIdx.x, lane = tid & 63, wid = tid >> 6;   // wid 0..3
  const int hi = lane >> 5, ln = lane & 31;
  const int qbw = qi * 128 + wid * 32;
  const int qg = qbw + ln;                    // this lane's q column

  const size_t kbase = (size_t)(b * 2048) * 1024 + h * 64;
  const size_t vbase = (size_t)bh * 131072;

  // Q B-fragments resident: 4 d-chunks of 16 (slot (hi,j) supplies d = dc*16 + 8*hi + j)
  bf16x8 qf[4];
  {
    const ushort* Qp = Qb + kbase + (size_t)qg * 1024 + hi * 8;
#pragma unroll
    for (int dc = 0; dc < 4; dc++)
      qf[dc] = *(const bf16x8*)(Qp + dc * 16);
  }

  f32x16 o_acc[2] = {};
  float l_own = 0.f;

  // staging: 4-way split (waves 0,1 -> K halves; 2,3 -> V halves); source group
  // pre-XOR'd by row&7 (LDS dest linear).
  const int krow = lane >> 3, kcol = lane & 7;
  const int dsw = (kcol ^ krow) << 3;          // swizzled element offset within row
  const int shalf = wid & 1;                   // row-half this wave stages

  auto stage = [&](int kb, int nb) {
    if (wid < 2) {
      const ushort* gK = Kb + kbase + (size_t)(kb + shalf * 32 + krow) * 1024 + dsw;
#pragma unroll
      for (int i = 0; i < 4; i++)
        g2l16(gK + (size_t)(i * 8) * 1024, &Ks[nb][(shalf * 4 + i) * 512]);
    } else {
      const ushort* gV = Vt + vbase + (size_t)(shalf * 32 + krow) * 2048 + kb + dsw;
#pragma unroll
      for (int i = 0; i < 4; i++)
        g2l16(gV + (size_t)(i * 8) * 2048, &Vs[nb][(shalf * 4 + i) * 512]);
    }
  };

  const int sx = ln & 7;                       // row&7 for this lane's reads

  stage(t0 * 64, 0);
  for (int kt = t0; kt < t1; kt++) {
    const int kb = kt * 64;
    const int nb = (kt - t0) & 1;
    __syncthreads();                           // drains prefetch (vmcnt) -> buf nb ready
    if (kt + 1 < t1) stage((kt + 1) * 64, nb ^ 1);  // prefetch overlaps compute below

#pragma unroll
    for (int g64 = 0; g64 < 2; g64++) {
      if (kb + g64 * 32 > qbw + 31) continue;  // half fully above diagonal (uniform)
      f32x16 s;
#pragma unroll
      for (int z = 0; z < 16; z++) s[z] = 0.f;
      // S^T(32 keys x 32 q) over d = 64 in 4 chunks of 16
      __builtin_amdgcn_s_setprio(1);
#pragma unroll
      for (int dc = 0; dc < 4; dc++) {
        bf16x8 kf = *(const bf16x8*)&Ks[nb][(g64 * 32 + ln) * 64 + (((dc * 2 + hi) ^ sx) << 3)];
        s = __builtin_amdgcn_mfma_f32_32x32x16_bf16(kf, qf[dc], s, 0, 0, 0);
      }
      __builtin_amdgcn_s_setprio(0);

      // softmax numerator: s[4g+j] = key_local 8g + 4hi + j (within this g64 half)
      unsigned U[8];
      const bool dmask = (kb + g64 * 32 + 31 > qbw);  // wave-uniform diagonal test
      if (dmask) {
        const int c = qg - kb - g64 * 32 - hi * 4;    // allowed iff g*8+j <= c
#pragma unroll
        for (int g = 0; g < 4; g++) {
          float e[4];
#pragma unroll
          for (int j = 0; j < 4; j++) {
            float sv = s[g * 4 + j];
            if (g * 8 + j > c) sv = -1e30f;
            e[j] = __builtin_amdgcn_exp2f(sv);
          }
          l_own += (e[0] + e[1]) + (e[2] + e[3]);
          union { float f; unsigned u; } f0{e[0]}, f1{e[1]}, f2{e[2]}, f3{e[3]};
          U[g * 2]     = __builtin_amdgcn_perm(f1.u + 0x8000u, f0.u + 0x8000u, 0x07060302u);
          U[g * 2 + 1] = __builtin_amdgcn_perm(f3.u + 0x8000u, f2.u + 0x8000u, 0x07060302u);
        }
      } else {
#pragma unroll
        for (int g = 0; g < 4; g++) {
          float e[4];
#pragma unroll
          for (int j = 0; j < 4; j++)
            e[j] = __builtin_amdgcn_exp2f(s[g * 4 + j]);
          l_own += (e[0] + e[1]) + (e[2] + e[3]);
          union { float f; unsigned u; } f0{e[0]}, f1{e[1]}, f2{e[2]}, f3{e[3]};
          U[g * 2]     = __builtin_amdgcn_perm(f1.u + 0x8000u, f0.u + 0x8000u, 0x07060302u);
          U[g * 2 + 1] = __builtin_amdgcn_perm(f3.u + 0x8000u, f2.u + 0x8000u, 0x07060302u);
        }
      }

      // O += P V, fragments m = 2*g64 + half; keymap as r3 (no cross-lane P movement)
      __builtin_amdgcn_s_setprio(1);
#pragma unroll
      for (int half = 0; half < 2; half++) {
        const int m = g64 * 2 + half;
        bf16x8 pfrag;
#pragma unroll
        for (int w = 0; w < 4; w++) ((unsigned*)&pfrag)[w] = U[half * 4 + w];
#pragma unroll
        for (int dg = 0; dg < 2; dg++) {
          const ushort* vrow = &Vs[nb][(dg * 32 + ln) * 64];
          bf16x8 vbf;
          *(unsigned long long*)&vbf =
              *(const unsigned long long*)&vrow[(((2 * m) ^ sx) << 3) + 4 * hi];
          *((unsigned long long*)&vbf + 1) =
              *(const unsigned long long*)&vrow[(((2 * m + 1) ^ sx) << 3) + 4 * hi];
          o_acc[dg] = __builtin_amdgcn_mfma_f32_32x32x16_bf16(pfrag, vbf, o_acc[dg], 0, 0, 0);
        }
      }
      __builtin_amdgcn_s_setprio(0);
    }
  }

  // l: combine hi halves (lane <-> lane^32 hold complementary key sets, same q)
  {
    float lt = l_own + __shfl_xor(l_own, 32);
    if (hi == 0) atomicAdd(&L32[(size_t)bh * 2048 + qg], lt);
  }
  // O partials: PLAIN stores to this chunk's slice (sole writer; no RMW)
  if (ci == 0) {
#pragma unroll
    for (int r = 0; r < 16; r++) {
      int q = qbw + (r & 3) + ((r >> 2) << 3) + hi * 4;
      size_t orow = ((size_t)(b * 2048) + q) * 1024 + h * 64 + ln;
      S0[orow] = o_acc[0][r];
      S0[orow + 32] = o_acc[1][r];
    }
  } else {
    ushort* Sp = (ci == 1) ? S1 : (ci == 2) ? S2 : S3;
    const int roff = (ci == 1) ? 512 : (ci == 2) ? 1024 : 1536;
    const int rcnt = 2048 - roff;              // rows per batch in this slice
#pragma unroll
    for (int r = 0; r < 16; r++) {
      int q = qbw + (r & 3) + ((r >> 2) << 3) + hi * 4;
      size_t srow = ((size_t)(b * rcnt) + (q - roff)) * 1024 + h * 64 + ln;
      Sp[srow] = f2bf(o_acc[0][r]);
      Sp[srow + 32] = f2bf(o_acc[1][r]);
    }
  }
}

// ---------------- normalize: sum slices, /l -> bf16 attn_out ----------------
__global__ __launch_bounds__(256) void normalize_kernel(const float* __restrict__ S0,
                                                        const ushort* __restrict__ S1,
                                                        const ushort* __restrict__ S2,
                                                        const ushort* __restrict__ S3,
                                                        const float* __restrict__ L32,
                                                        ushort* __restrict__ Out) {
  const int row = blockIdx.x;            // 0..4095  (b*2048 + t)
  const int tid = threadIdx.x;
  const int col = tid * 4;
  const int b = row >> 11, t = row & 2047, h = col >> 6;
  const int qi = t >> 7;
  const int nch = (2 * qi + 9) >> 3;     // chunks this row received (1..4)
  float4 o = ((const float4*)(S0 + (size_t)row * 1024))[tid];
  if (nch > 1) {
    ushort4 p = ((const ushort4*)(S1 + ((size_t)(b * 1536) + t - 512) * 1024))[tid];
    o.x += bf2f(p.x); o.y += bf2f(p.y); o.z += bf2f(p.z); o.w += bf2f(p.w);
  }
  if (nch > 2) {
    ushort4 p = ((const ushort4*)(S2 + ((size_t)(b * 1024) + t - 1024) * 1024))[tid];
    o.x += bf2f(p.x); o.y += bf2f(p.y); o.z += bf2f(p.z); o.w += bf2f(p.w);
  }
  if (nch > 3) {
    ushort4 p = ((const ushort4*)(S3 + ((size_t)(b * 512) + t - 1536) * 1024))[tid];
    o.x += bf2f(p.x); o.y += bf2f(p.y); o.z += bf2f(p.z); o.w += bf2f(p.w);
  }
  const float inv = 1.0f / L32[(size_t)(b * 16 + h) * 2048 + t];
  ushort4 u;
  u.x = f2bf(o.x * inv); u.y = f2bf(o.y * inv);
  u.z = f2bf(o.z * inv); u.w = f2bf(o.w * inv);
  ((ushort4*)(Out + (size_t)row * 1024))[tid] = u;
}

// ---------------- launcher ----------------
extern "C" void kernel_launch(void* const* d_in, const int* in_sizes, int n_in,
                              void* d_out, int out_size, void* d_ws, size_t ws_size,
                              hipStream_t stream) {
  const float* x  = (const float*)d_in[0];
  const float* Wq = (const float*)d_in[1];
  const float* Wk = (const float*)d_in[2];
  const float* Wv = (const float*)d_in[3];
  const float* Wo = (const float*)d_in[4];
  const float* bo = (const float*)d_in[5];
  float* out = (float*)d_out;

  char* ws = (char*)d_ws;
  ushort* xbf  = (ushort*)(ws);                  //  8 MB: x bf16 (dead after gemm_qkv)
  ushort* wcat = (ushort*)(ws + (8ull  << 20));  //  8 MB: Wcat bf16 (rows<3072 dead after qkv)
  ushort* qkv  = (ushort*)(ws + (16ull << 20));  // 24 MB: Q | K | Vt planes
  ushort* Qp   = qkv;
  ushort* Kp   = qkv + (1ull << 22);
  ushort* Vt   = qkv + (2ull << 22);             // V written directly transposed
  // partial slices in dead space [ws, ws+14MB): xbf + dead QKV-weight rows of wcat
  ushort* S1   = (ushort*)(ws);                  // 6 MB: rows q>=512  (bf16)
  ushort* S2   = (ushort*)(ws + (6ull  << 20));  // 4 MB: rows q>=1024 (bf16)
  ushort* S3   = (ushort*)(ws + (10ull << 20));  // 2 MB: rows q>=1536 (bf16)
  float*  L32  = (float*)(ws + (12ull << 20));   // 256 KB (dead wcat rows)
  float*  S0   = out;                            // d_out as f32 slice-0 scratch
  ushort* attn_out = Qp;                         // Q plane free after attn

  // cast x+weights (8192 blocks = 2M threads)
  cast_all<<<8192, 256, 0, stream>>>(x, Wq, Wk, Wv, Wo, xbf, wcat);

  // QKV = x @ Wcat[0:3072]^T; Q pre-scaled by 0.125*log2e; V transposed in epilogue via LDS
  gemm_qkv<<<dim3(24, 32), 256, 0, stream>>>(xbf, wcat, qkv, Vt);

  hipMemsetAsync(L32, 0, (size_t)32 * 2048 * 4, stream);

  attn_kernel<<<dim3(32, 40), 256, 0, stream>>>(Qp, Kp, Vt, S0, S1, S2, S3, L32);

  normalize_kernel<<<4096, 256, 0, stream>>>(S0, S1, S2, S3, L32, attn_out);

  // out = attn_out @ Wo^T + bo   (overwrites S0 scratch, stream-ordered)
  gemm_proj<<<dim3(16, 32), 256, 0, stream>>>(
      attn_out, wcat + (size_t)3072 * 1024, out, bo);
}